// Round 2
// baseline (526.385 us; speedup 1.0000x reference)
//
#include <hip/hip_runtime.h>
#include <hip/hip_bf16.h>

// Problem: B=256, T=64, S=16, U=4.
// x: (B, T, 16, 16) fp32 ; W: (P=256, O=1024, K=64) fp32 ; bias: (256, 1024) fp32
// out: (B, T, 64, 64) fp32
// y[p,b,o] = sum_k x[b,k,p] * W[p,o,k] + bias[p,o]
// out[b][t][si*4+ui][sj*4+uj], o = t*16 + ui*4 + uj, p = si*16 + sj
//
// Round-2 structure: MFMA roles swapped (A = W with m=o_local, B = xp with n=batch)
// so C/D reg index = uj -> each lane stores a contiguous float4 of out, and one
// wave's 4 pixels complete each 64B sector from the SAME lane (L2 write-merge safe).
// No LDS in the GEMM; A/B fragments load straight from global (8 contiguous elems/lane).

#define P_PIX 256
#define BATCH 256
#define KDIM 64
#define ODIM 1024

using bf16x8 = __attribute__((ext_vector_type(8))) short;
using f32x4  = __attribute__((ext_vector_type(4))) float;

// ---------------- Kernel 1: transpose + convert x -> xp (P, B*T) bf16 ----------------
// x viewed as (R=16384, P=256) row-major; xp[p][r] = bf16(x[r][p]).
__global__ __launch_bounds__(256) void transpose_convert(
    const float* __restrict__ x, __hip_bfloat16* __restrict__ xp)
{
    __shared__ float tile[64][65];
    const int R = BATCH * KDIM;  // 16384
    int p0 = (blockIdx.x & 3) * 64;
    int r0 = (blockIdx.x >> 2) * 64;
    int tp = threadIdx.x & 63;
    int t4 = threadIdx.x >> 6;  // 0..3
    #pragma unroll
    for (int i = 0; i < 16; ++i) {
        int r = t4 + i * 4;
        tile[r][tp] = x[(size_t)(r0 + r) * P_PIX + p0 + tp];
    }
    __syncthreads();
    #pragma unroll
    for (int i = 0; i < 16; ++i) {
        int pl = t4 + i * 4;
        xp[(size_t)(p0 + pl) * R + r0 + tp] = __float2bfloat16(tile[tp][pl]);
    }
}

// ---------------- Kernel 2: per-pixel GEMM, W as A-operand, direct-from-global ----------
// Block = (si, t, mt): 16 pixels (4/wave), o-range = t*16..t*16+16, batch-range = mt*64..+64.
// Grid order: mt innermost (4 blocks sharing the same W tile dispatch adjacently).
__global__ __launch_bounds__(256, 2) void gemm_pixel(
    const __hip_bfloat16* __restrict__ xp,  // (256, 256, 64) bf16
    const float* __restrict__ W,            // (256, 1024, 64) fp32
    const float* __restrict__ bias,         // (256, 1024) fp32
    float* __restrict__ out)                // (256, 64, 64, 64) fp32
{
    int g  = blockIdx.x;
    int mt = g & 3;          // batch tile (innermost: W reuse in L2)
    int t  = (g >> 2) & 63;  // output channel block
    int si = g >> 8;         // 0..15

    int tid  = threadIdx.x;
    int w    = tid >> 6;     // wave 0..3 -> sj group
    int lane = tid & 63;
    int lrow = lane & 15;
    int quad = lane >> 4;
    int b0   = mt * 64;

    f32x4 acc[4][4] = {};  // [pp][j]

    #pragma unroll
    for (int pp = 0; pp < 4; ++pp) {
        int p = si * 16 + w * 4 + pp;

        // ---- A fragments: W[p][t*16 + lrow][k], fp32 -> bf16, k = ks*32 + quad*8 .. +8
        const float* wrow = W + ((size_t)p * ODIM + (size_t)t * 16 + lrow) * KDIM;
        bf16x8 af[2];
        #pragma unroll
        for (int ks = 0; ks < 2; ++ks) {
            float4 u0 = *(const float4*)(wrow + ks * 32 + quad * 8);
            float4 u1 = *(const float4*)(wrow + ks * 32 + quad * 8 + 4);
            __hip_bfloat16 h[8];
            h[0] = __float2bfloat16(u0.x); h[1] = __float2bfloat16(u0.y);
            h[2] = __float2bfloat16(u0.z); h[3] = __float2bfloat16(u0.w);
            h[4] = __float2bfloat16(u1.x); h[5] = __float2bfloat16(u1.y);
            h[6] = __float2bfloat16(u1.z); h[7] = __float2bfloat16(u1.w);
            af[ks] = *(const bf16x8*)h;
        }

        // ---- B fragments: xp[p][b0 + j*16 + lrow][k], bf16 direct 16B loads
        const __hip_bfloat16* xbase = xp + (size_t)p * (BATCH * KDIM);
        #pragma unroll
        for (int j = 0; j < 4; ++j) {
            const __hip_bfloat16* xrow = xbase + (size_t)(b0 + j * 16 + lrow) * KDIM;
            #pragma unroll
            for (int ks = 0; ks < 2; ++ks) {
                bf16x8 bf = *(const bf16x8*)(xrow + ks * 32 + quad * 8);
                acc[pp][j] = __builtin_amdgcn_mfma_f32_16x16x32_bf16(af[ks], bf, acc[pp][j], 0, 0, 0);
            }
        }
    }

    // ---- Epilogue: bias + pixel-shuffle scatter, one float4 store per (pp, j) ----
    // C/D: col(n) = lane&15 -> b_local ; row(m) = quad*4 + reg -> o_local = ui*4 + uj
    //  => ui = quad, uj = reg. Lane's float4 = out[b][t][si*4+quad][sj*4 .. sj*4+4).
    #pragma unroll
    for (int pp = 0; pp < 4; ++pp) {
        int p  = si * 16 + w * 4 + pp;
        int sj = w * 4 + pp;
        float4 bv = *(const float4*)(bias + (size_t)p * ODIM + (size_t)t * 16 + quad * 4);
        #pragma unroll
        for (int j = 0; j < 4; ++j) {
            int b = b0 + j * 16 + lrow;
            float4 v;
            v.x = acc[pp][j][0] + bv.x;
            v.y = acc[pp][j][1] + bv.y;
            v.z = acc[pp][j][2] + bv.z;
            v.w = acc[pp][j][3] + bv.w;
            size_t off = ((((size_t)b * 64 + t) * 64) + si * 4 + quad) * 64 + sj * 4;
            *(float4*)(out + off) = v;
        }
    }
}

extern "C" void kernel_launch(void* const* d_in, const int* in_sizes, int n_in,
                              void* d_out, int out_size, void* d_ws, size_t ws_size,
                              hipStream_t stream) {
    const float* x    = (const float*)d_in[0];
    const float* W    = (const float*)d_in[1];
    const float* bias = (const float*)d_in[2];
    float* out = (float*)d_out;
    __hip_bfloat16* xp = (__hip_bfloat16*)d_ws;  // 256*256*64*2 = 8 MB

    transpose_convert<<<1024, 256, 0, stream>>>(x, xp);
    gemm_pixel<<<4096, 256, 0, stream>>>(xp, W, bias, out);
}